// Round 2
// baseline (634.852 us; speedup 1.0000x reference)
//
#include <hip/hip_runtime.h>
#include <stdint.h>

// Shapes (fixed by reference): B=32, S=2048, D=1024.
#define BDIM 32
#define SDIM 2048
#define DDIM 1024
#define MDIM (BDIM * SDIM)   // 65536 rows of the GEMM

typedef __bf16 bf16x8 __attribute__((ext_vector_type(8)));
typedef float  f32x4  __attribute__((ext_vector_type(4)));

// ---------- helpers ----------

__device__ inline unsigned short f2bf(float f) {
  union { float f; unsigned u; } un; un.f = f;
  unsigned r = un.u + 0x7fffu + ((un.u >> 16) & 1u);   // RNE
  return (unsigned short)(r >> 16);
}

__device__ inline float fast_tanh(float x) {
  float e = __expf(2.0f * x);
  return 1.0f - 2.0f / (e + 1.0f);
}

__device__ inline void gl_lds16(const unsigned short* g, unsigned short* l) {
  __builtin_amdgcn_global_load_lds(
      (__attribute__((address_space(1))) unsigned int*)(void*)(uintptr_t)g,
      (__attribute__((address_space(3))) unsigned int*)l,
      16, 0, 0);
}

// ---------- kernel 1: fp32 -> bf16 convert (8 elems/thread) ----------

__global__ __launch_bounds__(256) void cvt_kernel(const float* __restrict__ src,
                                                  unsigned short* __restrict__ dst) {
  size_t i = (size_t)blockIdx.x * 256 + threadIdx.x;
  const float4* s4 = (const float4*)src;
  float4 a = s4[2 * i];
  float4 b = s4[2 * i + 1];
  uint4 o;
  o.x = (unsigned)f2bf(a.x) | ((unsigned)f2bf(a.y) << 16);
  o.y = (unsigned)f2bf(a.z) | ((unsigned)f2bf(a.w) << 16);
  o.z = (unsigned)f2bf(b.x) | ((unsigned)f2bf(b.y) << 16);
  o.w = (unsigned)f2bf(b.z) | ((unsigned)f2bf(b.w) << 16);
  ((uint4*)dst)[i] = o;
}

// ---------- kernel 2: bf16 GEMM (128x128 tile, BK=64, 16x16x32 MFMA) ----------
// logits[m] += sum_n tanh( sum_k A[m][k]*W[n][k] ) * v[n]
// LDS layout: XOR-swizzled at 16B granularity. Logical (row, colchunk cc of 8
// bf16) lives at physical element (row*64 + (cc ^ (row&7))*8). The staging
// global read is permuted per-lane so global_load_lds's fixed base+lane*16B
// store produces exactly this layout. Fragment ds_read_b128s then hit each of
// the 32 banks exactly 8x per wave access (minimum for 1KB) -> no conflicts.

__global__ __launch_bounds__(256) void gemm_logits(
    const unsigned short* __restrict__ A,   // [M][1024] bf16 context
    const unsigned short* __restrict__ Bw,  // [1024][1024] bf16 W
    const float* __restrict__ v,
    float* __restrict__ logits)             // [M], pre-zeroed
{
  __shared__ __align__(16) unsigned short Al[128 * 64];   // 16 KB
  __shared__ __align__(16) unsigned short Bl[128 * 64];   // 16 KB

  const int t  = threadIdx.x;
  const int mt = blockIdx.x >> 3;
  const int nt = blockIdx.x & 7;
  const int m0 = mt * 128;
  const int n0 = nt * 128;
  const int w    = t >> 6;
  const int lane = t & 63;
  const int wm = (w >> 1) * 64;   // wave row offset in tile
  const int wn = (w & 1) * 64;    // wave col offset in tile
  const int c = lane & 15;        // frag col
  const int q = lane >> 4;        // frag quad

  float vv[4];
#pragma unroll
  for (int ni = 0; ni < 4; ++ni) vv[ni] = v[n0 + wn + ni * 16 + c];

  f32x4 acc[4][4] = {};

  // Staging: pass p (0..3) covers rows p*32..p*32+31. Thread t -> row
  // p*32 + (t>>3), logical colchunk (t&7)^((t>>3)&7), 16B each.
  const int srow = t >> 3;                       // 0..31
  const int scc  = ((t & 7) ^ (srow & 7)) * 8;   // swizzled element offset
  const unsigned short* gA[4];
  const unsigned short* gB[4];
  unsigned short* lA[4];
  unsigned short* lB[4];
#pragma unroll
  for (int p = 0; p < 4; ++p) {
    gA[p] = A  + (size_t)(m0 + p * 32 + srow) * DDIM + scc;
    gB[p] = Bw + (size_t)(n0 + p * 32 + srow) * DDIM + scc;
    lA[p] = Al + p * 2048 + w * 512;   // wave-uniform base; HW adds lane*16B
    lB[p] = Bl + p * 2048 + w * 512;
  }

  // Fragment read offsets (elements), physical = row*64 + ((ks*4+q)^(c&7))*8
  const int xr = c & 7;
  int arow[4], brow[4], koff[2];
#pragma unroll
  for (int mi = 0; mi < 4; ++mi) arow[mi] = (wm + mi * 16 + c) * 64;
#pragma unroll
  for (int ni = 0; ni < 4; ++ni) brow[ni] = (wn + ni * 16 + c) * 64;
#pragma unroll
  for (int ks = 0; ks < 2; ++ks) koff[ks] = ((ks * 4 + q) ^ xr) * 8;

  for (int kt = 0; kt < 16; ++kt) {
    const int k0 = kt * 64;
#pragma unroll
    for (int p = 0; p < 4; ++p) {
      gl_lds16(gA[p] + k0, lA[p]);
      gl_lds16(gB[p] + k0, lB[p]);
    }
    __syncthreads();

#pragma unroll
    for (int ks = 0; ks < 2; ++ks) {
      bf16x8 af[4], bfr[4];
#pragma unroll
      for (int mi = 0; mi < 4; ++mi)
        af[mi] = *(const bf16x8*)&Al[arow[mi] + koff[ks]];
#pragma unroll
      for (int ni = 0; ni < 4; ++ni)
        bfr[ni] = *(const bf16x8*)&Bl[brow[ni] + koff[ks]];

#pragma unroll
      for (int mi = 0; mi < 4; ++mi)
#pragma unroll
        for (int ni = 0; ni < 4; ++ni)
          acc[mi][ni] = __builtin_amdgcn_mfma_f32_16x16x32_bf16(
              af[mi], bfr[ni], acc[mi][ni], 0, 0, 0);
    }

    __syncthreads();
  }

  // Epilogue: tanh, dot with v over this wave's 64 columns, reduce, atomicAdd.
  // C/D layout (16x16): col = lane&15, row = (lane>>4)*4 + reg.
#pragma unroll
  for (int mi = 0; mi < 4; ++mi) {
    float p0 = 0.f, p1 = 0.f, p2 = 0.f, p3 = 0.f;
#pragma unroll
    for (int ni = 0; ni < 4; ++ni) {
      const float vvn = vv[ni];
      p0 += fast_tanh(acc[mi][ni][0]) * vvn;
      p1 += fast_tanh(acc[mi][ni][1]) * vvn;
      p2 += fast_tanh(acc[mi][ni][2]) * vvn;
      p3 += fast_tanh(acc[mi][ni][3]) * vvn;
    }
#pragma unroll
    for (int mask = 1; mask <= 8; mask <<= 1) {
      p0 += __shfl_xor(p0, mask);
      p1 += __shfl_xor(p1, mask);
      p2 += __shfl_xor(p2, mask);
      p3 += __shfl_xor(p3, mask);
    }
    if (c == 0) {
      float* lp = logits + (m0 + wm + mi * 16 + q * 4);
      atomicAdd(lp + 0, p0);
      atomicAdd(lp + 1, p1);
      atomicAdd(lp + 2, p2);
      atomicAdd(lp + 3, p3);
    }
  }
}

// ---------- kernel 3: per-batch softmax (in place over logits) ----------

__global__ __launch_bounds__(256) void softmax_kernel(float* __restrict__ la) {
  const int b = blockIdx.x;
  const int t = threadIdx.x;
  float* p = la + (size_t)b * SDIM;
  float x[8];
#pragma unroll
  for (int i = 0; i < 8; ++i) x[i] = p[i * 256 + t];
  float m = x[0];
#pragma unroll
  for (int i = 1; i < 8; ++i) m = fmaxf(m, x[i]);
#pragma unroll
  for (int mask = 1; mask < 64; mask <<= 1) m = fmaxf(m, __shfl_xor(m, mask));
  __shared__ float redm[4], reds[4];
  const int w = t >> 6, lane = t & 63;
  if (lane == 0) redm[w] = m;
  __syncthreads();
  m = fmaxf(fmaxf(redm[0], redm[1]), fmaxf(redm[2], redm[3]));
  float e[8];
  float s = 0.f;
#pragma unroll
  for (int i = 0; i < 8; ++i) { e[i] = __expf(x[i] - m); s += e[i]; }
#pragma unroll
  for (int mask = 1; mask < 64; mask <<= 1) s += __shfl_xor(s, mask);
  if (lane == 0) reds[w] = s;
  __syncthreads();
  s = reds[0] + reds[1] + reds[2] + reds[3];
  const float inv = 1.0f / s;
#pragma unroll
  for (int i = 0; i < 8; ++i) p[i * 256 + t] = e[i] * inv;
}

// ---------- kernel 4: weighted context sum ----------
// wc[b][d] = sum_s attn[b][s] * ctx[b][s][d]; grid = 32 batches * 32 s-chunks
// of 64 rows. attn chunk staged in LDS (broadcast reads), s-loop unrolled 4x
// with independent accumulators to keep >=4 wave-loads in flight.

__global__ __launch_bounds__(256) void wsum_kernel(const float* __restrict__ ctx,
                                                   const float* __restrict__ attn,
                                                   float* __restrict__ wc) {
  const int b  = blockIdx.x >> 5;
  const int sc = blockIdx.x & 31;
  const int t  = threadIdx.x;
  __shared__ float as_[64];
  if (t < 64) as_[t] = attn[(size_t)b * SDIM + sc * 64 + t];
  __syncthreads();
  const float* cp = ctx + ((size_t)b * SDIM + sc * 64) * DDIM + t * 4;
  float4 a0 = {0.f, 0.f, 0.f, 0.f}, a1 = a0, a2 = a0, a3 = a0;
#pragma unroll 4
  for (int s = 0; s < 64; s += 4) {
    const float4 c0 = *(const float4*)(cp + (size_t)(s + 0) * DDIM);
    const float4 c1 = *(const float4*)(cp + (size_t)(s + 1) * DDIM);
    const float4 c2 = *(const float4*)(cp + (size_t)(s + 2) * DDIM);
    const float4 c3 = *(const float4*)(cp + (size_t)(s + 3) * DDIM);
    const float w0 = as_[s], w1 = as_[s + 1], w2 = as_[s + 2], w3 = as_[s + 3];
    a0.x += w0 * c0.x; a0.y += w0 * c0.y; a0.z += w0 * c0.z; a0.w += w0 * c0.w;
    a1.x += w1 * c1.x; a1.y += w1 * c1.y; a1.z += w1 * c1.z; a1.w += w1 * c1.w;
    a2.x += w2 * c2.x; a2.y += w2 * c2.y; a2.z += w2 * c2.z; a2.w += w2 * c2.w;
    a3.x += w3 * c3.x; a3.y += w3 * c3.y; a3.z += w3 * c3.z; a3.w += w3 * c3.w;
  }
  a0.x += a1.x + a2.x + a3.x;
  a0.y += a1.y + a2.y + a3.y;
  a0.z += a1.z + a2.z + a3.z;
  a0.w += a1.w + a2.w + a3.w;
  float* o = wc + (size_t)b * DDIM + t * 4;
  atomicAdd(o + 0, a0.x);
  atomicAdd(o + 1, a0.y);
  atomicAdd(o + 2, a0.z);
  atomicAdd(o + 3, a0.w);
}

// ---------- launch ----------

extern "C" void kernel_launch(void* const* d_in, const int* in_sizes, int n_in,
                              void* d_out, int out_size, void* d_ws, size_t ws_size,
                              hipStream_t stream) {
  const float* ctx = (const float*)d_in[0];   // [32,2048,1024] fp32
  const float* W   = (const float*)d_in[1];   // [1024,1024] fp32
  const float* v   = (const float*)d_in[2];   // [1024] fp32
  // d_in[3] = scalar b: softmax-invariant, unused.

  float* out_wc   = (float*)d_out;            // [32,1024]
  float* out_attn = out_wc + BDIM * DDIM;     // [32,2048] (logits, then attn)

  unsigned short* ctx_bf = (unsigned short*)d_ws;           // 128 MB
  unsigned short* W_bf   = ctx_bf + (size_t)MDIM * DDIM;    // 2 MB

  hipMemsetAsync(d_out, 0, (size_t)out_size * sizeof(float), stream);

  cvt_kernel<<<(MDIM * DDIM) / (256 * 8), 256, 0, stream>>>(ctx, ctx_bf);
  cvt_kernel<<<(DDIM * DDIM) / (256 * 8), 256, 0, stream>>>(W, W_bf);
  gemm_logits<<<(MDIM / 128) * (DDIM / 128), 256, 0, stream>>>(ctx_bf, W_bf, v, out_attn);
  softmax_kernel<<<BDIM, 256, 0, stream>>>(out_attn);
  wsum_kernel<<<BDIM * 32, 256, 0, stream>>>(ctx, out_attn, out_wc);
}